// Round 3
// baseline (25.001 us; speedup 1.0000x reference)
//
#include <hip/hip_runtime.h>
#include <math.h>

// Problem constants (from reference):
//   features: (B=8, C=64, L=8192) fp32
//   H=32, UNIT=512, W=544, nblocks=16
//   out: (B, H, L) fp32;  out[b,h,l] = corr(col l, col l+1+h) within block n=l/512
#define BB    8
#define CC    64
#define LL    8192
#define HH    32
#define UNIT  512
#define NBLK  16
#define EPSF  1e-12f

// Each workgroup handles half a window: 256 output columns + 32-column halo.
#define TCOLS 256
#define WCOLS 288   // TCOLS + HH;  288 % 32 == 0 -> bank-conflict-free rows

__global__ __launch_bounds__(256)
void tsm_kernel(const float* __restrict__ feat, float* __restrict__ out) {
    // Xs[c][w]: centered window columns. Row stride 288 floats (~0 mod 32 banks):
    // consecutive lanes (consecutive w) -> consecutive banks in every phase.
    __shared__ float Xs[CC][WCOLS];   // 73728 B
    __shared__ float nrm[WCOLS];      //  1152 B  (total ~74.9 KiB LDS)

    const int tid  = threadIdx.x;
    const int blk  = blockIdx.x;          // 0..255
    const int half = blk & 1;
    const int n    = (blk >> 1) & 15;
    const int b    = blk >> 5;

    const int col0 = n * UNIT + half * TCOLS;   // global l of window column 0

    // ---- stage window to LDS (coalesced float4, zero-fill past L) ----
    const float* fb = feat + (size_t)b * CC * LL;
    for (int idx = tid; idx < CC * (WCOLS / 4); idx += 256) {
        int c = idx / (WCOLS / 4);
        int j = idx - c * (WCOLS / 4);
        int w = 4 * j;
        int l = col0 + w;                 // l % 4 == 0, L % 4 == 0 -> all-or-nothing
        float4 v;
        if (l < LL) {
            v = *reinterpret_cast<const float4*>(fb + (size_t)c * LL + l);
        } else {
            v = make_float4(0.f, 0.f, 0.f, 0.f);
        }
        *reinterpret_cast<float4*>(&Xs[c][w]) = v;
    }
    __syncthreads();

    // ---- center across channels (in-place) + column norms ----
    for (int w = tid; w < WCOLS; w += 256) {
        float s = 0.f;
        #pragma unroll
        for (int c = 0; c < CC; ++c) s += Xs[c][w];
        float m = s * (1.0f / CC);
        float ns = 0.f;
        #pragma unroll
        for (int c = 0; c < CC; ++c) {
            float v = Xs[c][w] - m;
            Xs[c][w] = v;
            ns += v * v;
        }
        nrm[w] = sqrtf(ns);
    }
    __syncthreads();

    // ---- banded Gram: acc[h] = sum_c Xc[c][t] * Xc[c][t+1+h] ----
    float acc[HH];
    #pragma unroll
    for (int h = 0; h < HH; ++h) acc[h] = 0.f;

    const int t = tid;                    // local column 0..255
    #pragma unroll 4
    for (int c = 0; c < CC; ++c) {
        float a = Xs[c][t];
        #pragma unroll
        for (int h = 0; h < HH; ++h) {
            acc[h] += a * Xs[c][t + 1 + h];
        }
    }

    // ---- normalize + store (coalesced per h-row) ----
    const float rt = nrm[t];
    const int   gl = col0 + t;            // output position along L
    float* ob = out + (size_t)b * HH * LL + gl;
    #pragma unroll
    for (int h = 0; h < HH; ++h) {
        float denom = fmaxf(rt * nrm[t + 1 + h], EPSF);
        float corr  = acc[h] / denom;
        if (gl + 1 + h >= LL) corr = 0.f;  // matches reference band mask
        ob[(size_t)h * LL] = corr;
    }
}

extern "C" void kernel_launch(void* const* d_in, const int* in_sizes, int n_in,
                              void* d_out, int out_size, void* d_ws, size_t ws_size,
                              hipStream_t stream) {
    const float* feat = (const float*)d_in[0];
    float* out = (float*)d_out;
    // 256 blocks = B(8) * nblocks(16) * halves(2); 256 threads each.
    tsm_kernel<<<dim3(256), dim3(256), 0, stream>>>(feat, out);
}

// Round 4
// 19.209 us; speedup vs baseline: 1.3015x; 1.3015x over previous
//
#include <hip/hip_runtime.h>
#include <math.h>

// features: (B=8, C=64, L=8192) fp32; H=32, UNIT=512, W=544
// out: (B, H, L) fp32; out[b,h,l] = corr(col l, col l+1+h) within block n=l/512
#define BB    8
#define CC    64
#define LL    8192
#define HH    32
#define UNIT  512
#define EPSF  1e-12f

#define TCOLS 256          // output columns per workgroup (half a window)
#define WCOLS 288          // TCOLS + HH halo; 288 % 32 == 0 and WCOLS/4 = 72

// LDS plan (1 block/CU):
//   phase 1-2: xs[64][288] fp32 window          (73,728 B)
//   phase 3+ : part[4 waves][64 lanes][32] f4   (131,072 B)  -- overlaps xs
//   ms/ns[288] column stats persist separately  ( 2,304 B)
union ShMem {
    float  xs[CC][WCOLS];
    float4 part[4][64][32];
};

__global__ __launch_bounds__(256, 1)
void tsm_kernel(const float* __restrict__ feat, float* __restrict__ out) {
    __shared__ ShMem u;
    __shared__ float ms[WCOLS];
    __shared__ float ns[WCOLS];

    const int tid  = threadIdx.x;
    const int lane = tid & 63;
    const int wv   = tid >> 6;
    const int blk  = blockIdx.x;          // 0..255
    const int half = blk & 1;
    const int n    = (blk >> 1) & 15;
    const int b    = blk >> 5;
    const int col0 = n * UNIT + half * TCOLS;

    // ---- stage window to LDS (coalesced float4, zero-fill past L) ----
    const float* fb = feat + (size_t)b * CC * LL;
    for (int idx = tid; idx < CC * (WCOLS / 4); idx += 256) {
        int c = idx / (WCOLS / 4);
        int j = idx - c * (WCOLS / 4);
        int w = 4 * j;
        int l = col0 + w;                  // l%4==0, L%4==0 -> all-or-nothing
        float4 v = make_float4(0.f, 0.f, 0.f, 0.f);
        if (l < LL) v = *reinterpret_cast<const float4*>(fb + (size_t)c * LL + l);
        *reinterpret_cast<float4*>(&u.xs[c][w]) = v;
    }
    __syncthreads();

    // ---- column stats on RAW data: mean + centered norm (no write-back) ----
    // num = sum(x*x') - C*m*m';  norm^2 = sum(x*x) - C*m^2
    for (int w = tid; w < WCOLS; w += 256) {
        float s = 0.f, ss = 0.f;
        #pragma unroll
        for (int c = 0; c < CC; ++c) { float x = u.xs[c][w]; s += x; ss += x * x; }
        float m = s * (1.0f / CC);
        ms[w] = m;
        ns[w] = sqrtf(fmaxf(ss - (float)CC * m * m, 0.f));
    }

    // ---- banded Gram on RAW data, channel-split across waves ----
    // wave wv: channels [16*wv, 16*wv+16); lane: columns [4*lane, 4*lane+4)
    float acc[4][HH];
    #pragma unroll
    for (int j = 0; j < 4; ++j)
        #pragma unroll
        for (int h = 0; h < HH; ++h) acc[j][h] = 0.f;

    for (int cc = 0; cc < 16; ++cc) {
        const int c = wv * 16 + cc;
        const float4* xr = reinterpret_cast<const float4*>(&u.xs[c][0]);
        float w36[36];
        #pragma unroll
        for (int k = 0; k < 9; ++k)
            *reinterpret_cast<float4*>(&w36[4 * k]) = xr[lane + k];  // 9x ds_read_b128, 16B-aligned
        #pragma unroll
        for (int j = 0; j < 4; ++j) {
            float a = w36[j];
            #pragma unroll
            for (int h = 0; h < HH; ++h)
                acc[j][h] = fmaf(a, w36[j + 1 + h], acc[j][h]);
        }
    }
    __syncthreads();   // all waves done reading xs; xs area now reused as part[]

    // ---- write partials, XOR-swizzled ((lane&7) on the 16B-slot index) ----
    #pragma unroll
    for (int j = 0; j < 4; ++j)
        #pragma unroll
        for (int h4 = 0; h4 < 8; ++h4) {
            int q = j * 8 + h4;
            u.part[wv][lane][q ^ (lane & 7)] =
                make_float4(acc[j][4 * h4 + 0], acc[j][4 * h4 + 1],
                            acc[j][4 * h4 + 2], acc[j][4 * h4 + 3]);
        }
    __syncthreads();

    // ---- gather across waves: thread t owns column t (all 32 h) ----
    const int lp = tid >> 2;               // producer lane
    const int jp = tid & 3;                // producer sub-column
    float sum[HH];
    #pragma unroll
    for (int h = 0; h < HH; ++h) sum[h] = 0.f;
    #pragma unroll
    for (int w = 0; w < 4; ++w)
        #pragma unroll
        for (int h4 = 0; h4 < 8; ++h4) {
            float4 v = u.part[w][lp][(jp * 8 + h4) ^ (lp & 7)];
            sum[4 * h4 + 0] += v.x;
            sum[4 * h4 + 1] += v.y;
            sum[4 * h4 + 2] += v.z;
            sum[4 * h4 + 3] += v.w;
        }

    // ---- normalize + store (coalesced per h-row) ----
    const float mt = ms[tid];
    const float nt = ns[tid];
    const int   gl = col0 + tid;
    float* ob = out + (size_t)b * HH * LL + gl;
    #pragma unroll
    for (int h = 0; h < HH; ++h) {
        float num  = sum[h] - (float)CC * mt * ms[tid + 1 + h];
        float den  = fmaxf(nt * ns[tid + 1 + h], EPSF);
        float corr = num * __builtin_amdgcn_rcpf(den);
        if (gl + 1 + h >= LL) corr = 0.f;   // reference band mask
        ob[(size_t)h * LL] = corr;
    }
}

extern "C" void kernel_launch(void* const* d_in, const int* in_sizes, int n_in,
                              void* d_out, int out_size, void* d_ws, size_t ws_size,
                              hipStream_t stream) {
    const float* feat = (const float*)d_in[0];
    float* out = (float*)d_out;
    // 256 blocks = B(8) * nblocks(16) * halves(2); 256 threads each; 1 block/CU.
    tsm_kernel<<<dim3(256), dim3(256), 0, stream>>>(feat, out);
}

// Round 5
// 13.414 us; speedup vs baseline: 1.8638x; 1.4320x over previous
//
#include <hip/hip_runtime.h>
#include <math.h>

// features: (B=8, C=64, L=8192) fp32; H=32, UNIT=512, W=544
// out[b,h,l] = corr(col l, col l+1+h) within block n=l/512
#define BB    8
#define CC    64
#define LL    8192
#define HH    32
#define UNITL 512
#define TC    256          // output columns per workgroup (half a window)
#define WC    288          // TC + 32 halo
#define EPSF  1e-12f
#define BSTR  260          // band row stride (floats); 260*4 % 16 == 0

typedef __attribute__((ext_vector_type(8))) short bf16x8;
typedef __attribute__((ext_vector_type(4))) float f32x4;

// LDS plan (one 512-thread block per CU; grid 256):
//   u.xs  : fp32 window [64][288]           73,728 B  (phases 1-2)
//   u.band: banded Gram [32][260] f32       33,280 B  (phases 3-4, reuses xs)
//   xhi/xlo: transposed bf16 hi/lo [288][64] 2x36,864 B (XOR-swizzled rows)
//   ms/ns : column stats                      2,304 B
// total ~149.8 KiB
union U {
    float xs[CC][WC];
    float band[HH][BSTR];
};

__global__ __launch_bounds__(512, 1)
void tsm_kernel(const float* __restrict__ feat, float* __restrict__ out) {
    __shared__ U u;
    __shared__ short xhi[WC * CC];
    __shared__ short xlo[WC * CC];
    __shared__ float ms[WC];
    __shared__ float ns[WC];

    const int tid  = threadIdx.x;
    const int lane = tid & 63;
    const int wv   = tid >> 6;            // 0..7
    const int blk  = blockIdx.x;          // 0..255
    const int half = blk & 1;
    const int n    = (blk >> 1) & 15;
    const int b    = blk >> 5;
    const int col0 = n * UNITL + half * TC;

    // ---- phase 1: stage fp32 window (coalesced float4; zero-fill past L) ----
    const float* fb = feat + (size_t)b * CC * LL;
    #pragma unroll
    for (int it = 0; it < 9; ++it) {
        int f16 = it * 512 + tid;          // float4 slot 0..4607 (64 rows x 72)
        int c   = f16 / 72;
        int q   = f16 - c * 72;
        int l   = col0 + 4 * q;
        f32x4 v = {0.f, 0.f, 0.f, 0.f};
        if (l < LL) v = *reinterpret_cast<const f32x4*>(fb + (size_t)c * LL + l);
        *reinterpret_cast<f32x4*>(&u.xs[c][4 * q]) = v;
    }
    __syncthreads();

    // ---- phase 2a: column stats in fp32 (mean + centered norm) ----
    if (tid < WC) {
        int w = tid;
        float s = 0.f, ss = 0.f;
        #pragma unroll
        for (int c = 0; c < CC; ++c) { float x = u.xs[c][w]; s += x; ss += x * x; }
        float m = s * (1.0f / CC);
        ms[w] = m;
        ns[w] = sqrtf(fmaxf(ss - (float)CC * m * m, 0.f));
    }

    // ---- phase 2b: convert to transposed bf16 hi/lo, XOR-swizzled rows ----
    // task tau -> (c8, w): write Xt[w][8*c8 .. +8) as one b128
    #pragma unroll
    for (int it = 0; it < 5; ++it) {
        int tau = it * 512 + tid;
        if (tau < WC * 8) {
            int c8 = tau / WC;
            int w  = tau - c8 * WC;
            bf16x8 Hv, Lv;
            #pragma unroll
            for (int j = 0; j < 8; ++j) {
                float x = u.xs[c8 * 8 + j][w];
                unsigned ub = __float_as_uint(x);
                unsigned hr = (ub + 0x7FFFu + ((ub >> 16) & 1u)) >> 16;   // RNE bf16
                float hf = __uint_as_float(hr << 16);
                float lo = x - hf;                                        // exact
                unsigned lb = __float_as_uint(lo);
                unsigned lr = (lb + 0x7FFFu + ((lb >> 16) & 1u)) >> 16;
                Hv[j] = (short)hr;
                Lv[j] = (short)lr;
            }
            int idx = (w * 64 + c8 * 8) ^ ((w & 7) << 3);   // short-index swizzle
            *reinterpret_cast<bf16x8*>(&xhi[idx]) = Hv;
            *reinterpret_cast<bf16x8*>(&xlo[idx]) = Lv;
        }
    }
    __syncthreads();

    // ---- phase 3: banded Gram via MFMA (wave wv owns row-blocks 2wv, 2wv+1) ----
    {
        const int r16 = lane & 15;
        const int g   = lane >> 4;
        bf16x8 fhi[4][2], flo[4][2];
        #pragma unroll
        for (int bb = 0; bb < 4; ++bb) {
            int row  = 16 * (2 * wv + bb) + r16;     // Xt row (window col), <= 287
            int base = row * 64;
            int sw   = (row & 7) << 3;
            #pragma unroll
            for (int kk = 0; kk < 2; ++kk) {
                int idx = (base + (g + 4 * kk) * 8) ^ sw;
                fhi[bb][kk] = *reinterpret_cast<const bf16x8*>(&xhi[idx]);
                flo[bb][kk] = *reinterpret_cast<const bf16x8*>(&xlo[idx]);
            }
        }
        #pragma unroll
        for (int ii = 0; ii < 2; ++ii) {
            const int i = 2 * wv + ii;
            #pragma unroll
            for (int dj = 0; dj < 3; ++dj) {
                const int jb = ii + dj;              // local frag block index
                f32x4 acc = {0.f, 0.f, 0.f, 0.f};
                acc = __builtin_amdgcn_mfma_f32_16x16x32_bf16(fhi[ii][0], fhi[jb][0], acc, 0, 0, 0);
                acc = __builtin_amdgcn_mfma_f32_16x16x32_bf16(fhi[ii][1], fhi[jb][1], acc, 0, 0, 0);
                acc = __builtin_amdgcn_mfma_f32_16x16x32_bf16(fhi[ii][0], flo[jb][0], acc, 0, 0, 0);
                acc = __builtin_amdgcn_mfma_f32_16x16x32_bf16(fhi[ii][1], flo[jb][1], acc, 0, 0, 0);
                acc = __builtin_amdgcn_mfma_f32_16x16x32_bf16(flo[ii][0], fhi[jb][0], acc, 0, 0, 0);
                acc = __builtin_amdgcn_mfma_f32_16x16x32_bf16(flo[ii][1], fhi[jb][1], acc, 0, 0, 0);
                // C/D layout (m89-verified): col = lane&15, row = 4*(lane>>4)+reg
                #pragma unroll
                for (int r = 0; r < 4; ++r) {
                    int t  = 16 * i + 4 * g + r;              // 0..255
                    int tp = 16 * (i + dj) + r16;             // 0..287
                    int h  = tp - t - 1;
                    if ((unsigned)h < 32u) u.band[h][t] = acc[r];
                }
            }
        }
    }
    __syncthreads();

    // ---- phase 4: normalize + mask + coalesced store ----
    {
        const int h  = tid >> 4;           // 0..31
        const int cb = tid & 15;
        float* ob = out + ((size_t)b * HH + h) * LL + col0;
        #pragma unroll
        for (int k = 0; k < 4; ++k) {
            int c4 = cb + 16 * k;          // f4-chunk 0..63
            int t0 = 4 * c4;
            f32x4 v = *reinterpret_cast<const f32x4*>(&u.band[h][t0]);
            f32x4 res;
            #pragma unroll
            for (int e = 0; e < 4; ++e) {
                int t  = t0 + e;
                int tp = t + 1 + h;
                float num  = v[e] - (float)CC * ms[t] * ms[tp];
                float den  = fmaxf(ns[t] * ns[tp], EPSF);
                float corr = num * __builtin_amdgcn_rcpf(den);
                if (col0 + tp >= LL) corr = 0.f;   // reference band mask
                res[e] = corr;
            }
            *reinterpret_cast<f32x4*>(ob + t0) = res;
        }
    }
}

extern "C" void kernel_launch(void* const* d_in, const int* in_sizes, int n_in,
                              void* d_out, int out_size, void* d_ws, size_t ws_size,
                              hipStream_t stream) {
    const float* feat = (const float*)d_in[0];
    float* out = (float*)d_out;
    // 256 blocks = B(8) x nblocks(16) x halves(2); 512 threads (8 waves) each.
    tsm_kernel<<<dim3(256), dim3(512), 0, stream>>>(feat, out);
}